// Round 3
// baseline (3903.623 us; speedup 1.0000x reference)
//
#include <hip/hip_runtime.h>
#include <hip/hip_bf16.h>

typedef __hip_bfloat16 bf16;

#define NNODES 118784
#define NEDGES 3000000
#define INDIM 116
#define EMBD 16
#define HID 64
#define NGRAPH 1024
#define ROIS 116

__device__ __forceinline__ float b2f(bf16 v) { return __bfloat162float(v); }
__device__ __forceinline__ bf16 f2b(float v) { return __float2bfloat16(v); }

// ---------------------------------------------------------------------------
// Encoder: a = relu(concat(x, emb[gid]) @ W_enc + b_enc) -> hb (bf16, pre-BN)
// accumulates per-channel sum / sumsq (fp32, unrounded) into stats
// ---------------------------------------------------------------------------
__global__ __launch_bounds__(256) void enc_kernel(
    const float* __restrict__ x, const int* __restrict__ gid,
    const float* __restrict__ emb, const float* __restrict__ Wenc,
    const float* __restrict__ benc,
    bf16* __restrict__ hb, float* __restrict__ stats)
{
    __shared__ float Wl[(INDIM + EMBD) * HID];   // 33792 B
    for (int i = threadIdx.x; i < (INDIM + EMBD) * HID; i += 256)
        Wl[i] = Wenc[i];
    __syncthreads();

    const int lane = threadIdx.x & 63;
    const int wid  = (blockIdx.x * 256 + threadIdx.x) >> 6;
    const int nw   = (gridDim.x * 256) >> 6;
    const float bb = benc[lane];

    float lsum = 0.f, lsq = 0.f;
    for (int n = wid; n < NNODES; n += nw) {
        const float* xr = x + n * INDIM;
        float acc = bb;
        #pragma unroll 4
        for (int k = 0; k < INDIM; k++)
            acc += xr[k] * Wl[k * HID + lane];
        const int g = gid[n];
        const float* er = emb + g * EMBD;
        #pragma unroll
        for (int k = 0; k < EMBD; k++)
            acc += er[k] * Wl[(INDIM + k) * HID + lane];
        float a = fmaxf(acc, 0.f);
        hb[n * HID + lane] = f2b(a);
        lsum += a;
        lsq  += a * a;
    }
    unsafeAtomicAdd(&stats[lane], lsum);
    unsafeAtomicAdd(&stats[64 + lane], lsq);
}

// ---------------------------------------------------------------------------
// BN finalize (in place on hb): v = gamma*(v-m)*rsqrt(var+eps)+beta, opt relu
// ---------------------------------------------------------------------------
__global__ __launch_bounds__(256) void bn_kernel(
    bf16* __restrict__ hb, const float* __restrict__ stats,
    const float* __restrict__ gamma, const float* __restrict__ beta, int relu)
{
    const int idx = blockIdx.x * 256 + threadIdx.x;
    const int total = NNODES * HID;
    if (idx >= total) return;
    const int c = idx & 63;
    const float m   = stats[c] * (1.f / NNODES);
    const float var = stats[64 + c] * (1.f / NNODES) - m * m;
    const float inv = rsqrtf(var + 1e-5f);
    const float gg = gamma[c] * inv;
    const float bb = beta[c] - gg * m;
    float v = b2f(hb[idx]) * gg + bb;
    if (relu) v = fmaxf(v, 0.f);
    hb[idx] = f2b(v);
}

// ---------------------------------------------------------------------------
// Edge phase: m = relu(h[src] + ea @ We + be); agg[dst] += m
// One wave per edge, lane = channel. h is bf16 (128B gather/row).
// ---------------------------------------------------------------------------
__global__ __launch_bounds__(256) void edge_kernel(
    const bf16* __restrict__ hb, const float* __restrict__ ea,
    const int* __restrict__ src, const int* __restrict__ dst,
    const float* __restrict__ We, const float* __restrict__ be,
    float* __restrict__ agg)
{
    const int lane = threadIdx.x & 63;
    const int wid  = (blockIdx.x * 256 + threadIdx.x) >> 6;
    const int nw   = (gridDim.x * 256) >> 6;

    const float w0 = We[0 * 64 + lane];
    const float w1 = We[1 * 64 + lane];
    const float w2 = We[2 * 64 + lane];
    const float w3 = We[3 * 64 + lane];
    const float w4 = We[4 * 64 + lane];
    const float bb = be[lane];

    const int chunk = (NEDGES + nw - 1) / nw;
    const int e0 = wid * chunk;
    const int e1 = min(e0 + chunk, NEDGES);

    #pragma unroll 2
    for (int e = e0; e < e1; e++) {
        const int s = __builtin_amdgcn_readfirstlane(src[e]);
        const int d = __builtin_amdgcn_readfirstlane(dst[e]);
        const float* a = ea + e * 5;
        float v = bb + a[0] * w0 + a[1] * w1 + a[2] * w2
                     + a[3] * w3 + a[4] * w4
                     + b2f(hb[s * HID + lane]);
        v = fmaxf(v, 0.f);
        unsafeAtomicAdd(&agg[d * HID + lane], v);
    }
}

// ---------------------------------------------------------------------------
// Node phase: z = h + agg; t = relu(z@W1+b1); o = t@W2+b2
// DOBN=0: hb = relu(o).  DOBN=1: hb = o (pre-BN) + BN stats (fp32).
// Re-zeros agg for the next layer's scatter.
// ---------------------------------------------------------------------------
template <int DOBN>
__global__ __launch_bounds__(256) void node_kernel(
    bf16* __restrict__ hb, float* __restrict__ agg,
    const float* __restrict__ W1, const float* __restrict__ b1,
    const float* __restrict__ W2, const float* __restrict__ b2,
    float* __restrict__ stats)
{
    __shared__ float W1l[HID * HID];   // 16 KB
    __shared__ float W2l[HID * HID];   // 16 KB
    __shared__ float zs[4 * HID];
    for (int i = threadIdx.x; i < HID * HID; i += 256) {
        W1l[i] = W1[i];
        W2l[i] = W2[i];
    }
    __syncthreads();

    const int lane = threadIdx.x & 63;
    const int wv   = threadIdx.x >> 6;
    const int wid  = (blockIdx.x * 256 + threadIdx.x) >> 6;
    const int nw   = (gridDim.x * 256) >> 6;
    const float bb1 = b1[lane];
    const float bb2 = b2[lane];
    float* zrow = &zs[wv * HID];

    float lsum = 0.f, lsq = 0.f;
    for (int n = wid; n < NNODES; n += nw) {
        const int base = n * HID;
        const float z = b2f(hb[base + lane]) + agg[base + lane];
        agg[base + lane] = 0.f;           // re-zero for next layer's scatter

        __builtin_amdgcn_wave_barrier();
        zrow[lane] = z;
        __builtin_amdgcn_wave_barrier();
        float t = bb1;
        #pragma unroll 8
        for (int k = 0; k < HID; k++)
            t += zrow[k] * W1l[k * HID + lane];
        t = fmaxf(t, 0.f);

        __builtin_amdgcn_wave_barrier();
        zrow[lane] = t;
        __builtin_amdgcn_wave_barrier();
        float o = bb2;
        #pragma unroll 8
        for (int k = 0; k < HID; k++)
            o += zrow[k] * W2l[k * HID + lane];

        if (DOBN) {
            hb[base + lane] = f2b(o);     // pre-BN, normalized in bn_kernel
            lsum += o;
            lsq  += o * o;
        } else {
            hb[base + lane] = f2b(fmaxf(o, 0.f));
        }
    }
    if (DOBN) {
        unsafeAtomicAdd(&stats[lane], lsum);
        unsafeAtomicAdd(&stats[64 + lane], lsq);
    }
}

// ---------------------------------------------------------------------------
// Head: pooled = segsum over 116 contiguous rows; relu; @Wl1+bl1; @Wl2+bl2
// One block (128 threads) per graph.
// ---------------------------------------------------------------------------
__global__ __launch_bounds__(128) void head_kernel(
    const bf16* __restrict__ hb, const float* __restrict__ Wl1,
    const float* __restrict__ bl1, const float* __restrict__ Wl2,
    const float* __restrict__ bl2, float* __restrict__ out)
{
    __shared__ float part[2 * HID];
    __shared__ float ps[HID];
    __shared__ float r0[128], r1[128];

    const int g = blockIdx.x;
    const int tid = threadIdx.x;
    const int lane = tid & 63;
    const int wv = tid >> 6;
    const bf16* hbg = hb + g * ROIS * HID;

    float acc = 0.f;
    for (int r = wv; r < ROIS; r += 2)
        acc += b2f(hbg[r * HID + lane]);
    part[wv * HID + lane] = acc;
    __syncthreads();
    if (tid < HID) ps[tid] = fmaxf(part[tid] + part[HID + tid], 0.f);
    __syncthreads();

    float e0 = 0.f, e1 = 0.f;
    if (tid < ROIS) {
        float a = bl1[tid];
        #pragma unroll 8
        for (int c = 0; c < HID; c++)
            a += ps[c] * Wl1[c * ROIS + tid];
        e0 = a * Wl2[tid * 2 + 0];
        e1 = a * Wl2[tid * 2 + 1];
    }
    r0[tid] = e0;
    r1[tid] = e1;
    __syncthreads();
    for (int s = 64; s > 0; s >>= 1) {
        if (tid < s) { r0[tid] += r0[tid + s]; r1[tid] += r1[tid + s]; }
        __syncthreads();
    }
    if (tid == 0) {
        out[g * 2 + 0] = r0[0] + bl2[0];
        out[g * 2 + 1] = r1[0] + bl2[1];
    }
}

// ---------------------------------------------------------------------------
extern "C" void kernel_launch(void* const* d_in, const int* in_sizes, int n_in,
                              void* d_out, int out_size, void* d_ws, size_t ws_size,
                              hipStream_t stream)
{
    const float* x       = (const float*)d_in[0];
    const float* ea      = (const float*)d_in[1];
    const int*   eidx    = (const int*)  d_in[2];
    const int*   gid     = (const int*)  d_in[4];
    const float* emb     = (const float*)d_in[5];
    const float* Wenc    = (const float*)d_in[6];
    const float* benc    = (const float*)d_in[7];
    const float* gamma_e = (const float*)d_in[8];
    const float* beta_e  = (const float*)d_in[9];
    const float* We0     = (const float*)d_in[10];
    const float* be0     = (const float*)d_in[11];
    const float* W10     = (const float*)d_in[12];
    const float* b10     = (const float*)d_in[13];
    const float* W20     = (const float*)d_in[14];
    const float* b20     = (const float*)d_in[15];
    const float* We      = (const float*)d_in[16];
    const float* be      = (const float*)d_in[17];
    const float* W1      = (const float*)d_in[18];
    const float* b1      = (const float*)d_in[19];
    const float* W2      = (const float*)d_in[20];
    const float* b2      = (const float*)d_in[21];
    const float* gamma   = (const float*)d_in[22];
    const float* beta    = (const float*)d_in[23];
    const float* Wl1     = (const float*)d_in[24];
    const float* bl1     = (const float*)d_in[25];
    const float* Wl2     = (const float*)d_in[26];
    const float* bl2     = (const float*)d_in[27];

    const int* srcp = eidx;
    const int* dstp = eidx + NEDGES;

    // workspace: hb (bf16 N*H = 15.2MB) | agg (fp32 N*H = 30.4MB) | stats
    const size_t NH = (size_t)NNODES * HID;
    bf16*  hbuf   = (bf16*)d_ws;
    float* aggbuf = (float*)((char*)d_ws + NH * sizeof(bf16));
    float* stats  = aggbuf + NH;          // 5 sections of 128 floats

    hipMemsetAsync(aggbuf, 0, NH * sizeof(float), stream);
    hipMemsetAsync(stats, 0, 5 * 128 * sizeof(float), stream);

    const int elem_blocks = (NNODES * HID + 255) / 256;   // 29696

    // encoder + BN (relu inside enc, BN after — matches reference order)
    enc_kernel<<<2048, 256, 0, stream>>>(x, gid, emb, Wenc, benc, hbuf, stats);
    bn_kernel<<<elem_blocks, 256, 0, stream>>>(hbuf, stats, gamma_e, beta_e, 0);

    // GINE layer 0 (relu, no BN)
    edge_kernel<<<4096, 256, 0, stream>>>(hbuf, ea, srcp, dstp, We0, be0, aggbuf);
    node_kernel<0><<<2048, 256, 0, stream>>>(hbuf, aggbuf, W10, b10, W20, b20, nullptr);

    // GINE layers 1..3 (BN + relu)
    for (int l = 0; l < 3; l++) {
        edge_kernel<<<4096, 256, 0, stream>>>(hbuf, ea, srcp, dstp,
                                              We + l * 5 * 64, be + l * 64, aggbuf);
        node_kernel<1><<<2048, 256, 0, stream>>>(hbuf, aggbuf,
                                                 W1 + l * 64 * 64, b1 + l * 64,
                                                 W2 + l * 64 * 64, b2 + l * 64,
                                                 stats + 128 * (l + 1));
        bn_kernel<<<elem_blocks, 256, 0, stream>>>(hbuf, stats + 128 * (l + 1),
                                                   gamma, beta, 1);
    }

    // pooling + head
    head_kernel<<<NGRAPH, 128, 0, stream>>>(hbuf, Wl1, bl1, Wl2, bl2, (float*)d_out);
}

// Round 4
// 2396.283 us; speedup vs baseline: 1.6290x; 1.6290x over previous
//
#include <hip/hip_runtime.h>
#include <hip/hip_bf16.h>

typedef __hip_bfloat16 bf16;
typedef __attribute__((ext_vector_type(8))) short short8;
typedef __attribute__((ext_vector_type(4))) float floatx4;

#define NNODES 118784
#define NEDGES 3000000
#define INDIM 116
#define EMBD 16
#define HID 64
#define NGRAPH 1024
#define ROIS 116

__device__ __forceinline__ float b2f(bf16 v) { return __bfloat162float(v); }
__device__ __forceinline__ bf16 f2b(float v) { return __float2bfloat16(v); }
__device__ __forceinline__ unsigned short f2u(float v) {
    bf16 b = __float2bfloat16(v);
    return *reinterpret_cast<unsigned short*>(&b);
}

// ---------------------------------------------------------------------------
// Sort phase 1: histogram of dst
// ---------------------------------------------------------------------------
__global__ __launch_bounds__(256) void hist_kernel(
    const int* __restrict__ dst, int* __restrict__ cnt)
{
    int i = blockIdx.x * 256 + threadIdx.x;
    if (i < NEDGES) atomicAdd(&cnt[dst[i]], 1);
}

// ---------------------------------------------------------------------------
// Sort phase 2: exclusive scan of 118784 counts (1024 threads x 116 chunk)
// writes off[0..NNODES] and cursor copy
// ---------------------------------------------------------------------------
__global__ __launch_bounds__(1024) void scan_kernel(
    const int* __restrict__ cnt, int* __restrict__ off, int* __restrict__ cur)
{
    __shared__ int ps[1024];
    const int t = threadIdx.x;
    const int base = t * 116;
    int s = 0;
    for (int i = 0; i < 116; i++) s += cnt[base + i];
    ps[t] = s;
    __syncthreads();
    for (int d = 1; d < 1024; d <<= 1) {
        int v = (t >= d) ? ps[t - d] : 0;
        __syncthreads();
        ps[t] += v;
        __syncthreads();
    }
    int run = (t == 0) ? 0 : ps[t - 1];
    for (int i = 0; i < 116; i++) {
        off[base + i] = run;
        cur[base + i] = run;
        run += cnt[base + i];
    }
    if (t == 1023) off[NNODES] = run;   // = NEDGES
}

// ---------------------------------------------------------------------------
// Sort phase 3: scatter edges into dst-sorted order (order within a segment
// is arbitrary — aggregation is a sum)
// ---------------------------------------------------------------------------
__global__ __launch_bounds__(256) void scatter_kernel(
    const int* __restrict__ src, const int* __restrict__ dst,
    int* __restrict__ cur, int* __restrict__ ssrc, int* __restrict__ perm)
{
    int i = blockIdx.x * 256 + threadIdx.x;
    if (i >= NEDGES) return;
    int d = dst[i];
    int p = atomicAdd(&cur[d], 1);
    ssrc[p] = src[i];
    perm[p] = i;
}

// ---------------------------------------------------------------------------
// Encoder: a = relu(concat(x, emb[gid]) @ W_enc + b_enc) -> A (bf16, pre-BN)
// + per-channel sum/sumsq into stats
// ---------------------------------------------------------------------------
__global__ __launch_bounds__(256) void enc_kernel(
    const float* __restrict__ x, const int* __restrict__ gid,
    const float* __restrict__ emb, const float* __restrict__ Wenc,
    const float* __restrict__ benc,
    bf16* __restrict__ hb, float* __restrict__ stats)
{
    __shared__ float Wl[(INDIM + EMBD) * HID];
    for (int i = threadIdx.x; i < (INDIM + EMBD) * HID; i += 256)
        Wl[i] = Wenc[i];
    __syncthreads();

    const int lane = threadIdx.x & 63;
    const int wid  = (blockIdx.x * 256 + threadIdx.x) >> 6;
    const int nw   = (gridDim.x * 256) >> 6;
    const float bb = benc[lane];

    float lsum = 0.f, lsq = 0.f;
    for (int n = wid; n < NNODES; n += nw) {
        const float* xr = x + n * INDIM;
        float acc = bb;
        #pragma unroll 4
        for (int k = 0; k < INDIM; k++)
            acc += xr[k] * Wl[k * HID + lane];
        const int g = gid[n];
        const float* er = emb + g * EMBD;
        #pragma unroll
        for (int k = 0; k < EMBD; k++)
            acc += er[k] * Wl[(INDIM + k) * HID + lane];
        float a = fmaxf(acc, 0.f);
        hb[n * HID + lane] = f2b(a);
        lsum += a;
        lsq  += a * a;
    }
    unsafeAtomicAdd(&stats[lane], lsum);
    unsafeAtomicAdd(&stats[64 + lane], lsq);
}

// ---------------------------------------------------------------------------
// BN finalize in place, optional relu
// ---------------------------------------------------------------------------
__global__ __launch_bounds__(256) void bn_kernel(
    bf16* __restrict__ hb, const float* __restrict__ stats,
    const float* __restrict__ gamma, const float* __restrict__ beta, int relu)
{
    const int idx = blockIdx.x * 256 + threadIdx.x;
    if (idx >= NNODES * HID) return;
    const int c = idx & 63;
    const float m   = stats[c] * (1.f / NNODES);
    const float var = stats[64 + c] * (1.f / NNODES) - m * m;
    const float inv = rsqrtf(var + 1e-5f);
    const float gg = gamma[c] * inv;
    const float bb = beta[c] - gg * m;
    float v = b2f(hb[idx]) * gg + bb;
    if (relu) v = fmaxf(v, 0.f);
    hb[idx] = f2b(v);
}

// ---------------------------------------------------------------------------
// Gather-aggregate (no atomics): wave per node, lane = channel.
// z[n] = h[n] + sum_{e in in(n)} relu(h[src_e] + ea_e @ We + be)
// ---------------------------------------------------------------------------
__global__ __launch_bounds__(256) void agg_kernel(
    const bf16* __restrict__ hin, bf16* __restrict__ zout,
    const float* __restrict__ ea, const int* __restrict__ perm,
    const int* __restrict__ ssrc, const int* __restrict__ off,
    const float* __restrict__ We, const float* __restrict__ be)
{
    const int lane = threadIdx.x & 63;
    const int node = (blockIdx.x * 256 + threadIdx.x) >> 6;
    if (node >= NNODES) return;

    const float w0 = We[0 * 64 + lane];
    const float w1 = We[1 * 64 + lane];
    const float w2 = We[2 * 64 + lane];
    const float w3 = We[3 * 64 + lane];
    const float w4 = We[4 * 64 + lane];
    const float bb = be[lane];

    const int s0 = off[node];
    const int s1 = off[node + 1];

    float acc = 0.f;
    #pragma unroll 4
    for (int i = s0; i < s1; i++) {
        const int eid = perm[i];                      // broadcast (contiguous)
        const int s   = ssrc[i];                      // broadcast (contiguous)
        const float* a = ea + (size_t)eid * 5;        // random 20B (broadcast)
        const float h = b2f(hin[(size_t)s * HID + lane]);  // random 128B gather
        float v = bb + a[0] * w0 + a[1] * w1 + a[2] * w2
                     + a[3] * w3 + a[4] * w4 + h;
        acc += fmaxf(v, 0.f);
    }
    zout[(size_t)node * HID + lane] =
        f2b(b2f(hin[(size_t)node * HID + lane]) + acc);
}

// ---------------------------------------------------------------------------
// Node MLP via MFMA, in place on Z: o = relu(z@W1+b1)@W2+b2
// MODE 0: z <- relu(o).  MODE 1: z <- o (pre-BN) + stats.
// 64 nodes per block; wave w owns rows 16w..16w+15.
// ---------------------------------------------------------------------------
template <int MODE>
__global__ __launch_bounds__(256) void mlp_kernel(
    bf16* __restrict__ Zg,
    const float* __restrict__ W1, const float* __restrict__ b1,
    const float* __restrict__ W2, const float* __restrict__ b2,
    float* __restrict__ stats)
{
    __shared__ unsigned short Zl[64 * 72];   // 9 KB, stride 72 vs bank conflicts
    __shared__ unsigned short W1t[64 * 72];  // transposed: W1t[n][k] = W1[k][n]
    __shared__ unsigned short W2t[64 * 72];
    __shared__ unsigned short Tl[64 * 72];

    const int tid = threadIdx.x;
    const int r0 = blockIdx.x * 64;

    for (int i = tid; i < 4096; i += 256) {
        int k = i >> 6, n = i & 63;
        W1t[n * 72 + k] = f2u(W1[i]);
        W2t[n * 72 + k] = f2u(W2[i]);
    }
    {
        const uint4* zg = (const uint4*)(Zg + (size_t)r0 * HID);
        for (int i = tid; i < 512; i += 256) {        // 512 x 16B chunks
            int row = i >> 3, ch = i & 7;
            uint4 v = zg[row * 8 + ch];
            *(uint4*)&Zl[row * 72 + ch * 8] = v;
        }
    }
    __syncthreads();

    const int lane = tid & 63;
    const int wv   = tid >> 6;
    const int m    = lane & 15;     // row (A) / col (B,C)
    const int q    = lane >> 4;     // quad
    const int mrow = wv * 16;

    float bias1[4], bias2[4];
    #pragma unroll
    for (int c = 0; c < 4; c++) {
        bias1[c] = b1[c * 16 + m];
        bias2[c] = b2[c * 16 + m];
    }

    floatx4 acc[4];
    #pragma unroll
    for (int c = 0; c < 4; c++) acc[c] = {0.f, 0.f, 0.f, 0.f};
    #pragma unroll
    for (int s = 0; s < 2; s++) {
        short8 af = *(const short8*)&Zl[(mrow + m) * 72 + s * 32 + q * 8];
        #pragma unroll
        for (int c = 0; c < 4; c++) {
            short8 bfr = *(const short8*)&W1t[(c * 16 + m) * 72 + s * 32 + q * 8];
            acc[c] = __builtin_amdgcn_mfma_f32_16x16x32_bf16(af, bfr, acc[c], 0, 0, 0);
        }
    }
    #pragma unroll
    for (int c = 0; c < 4; c++)
        #pragma unroll
        for (int r = 0; r < 4; r++)
            Tl[(mrow + q * 4 + r) * 72 + c * 16 + m] =
                f2u(fmaxf(acc[c][r] + bias1[c], 0.f));
    __syncthreads();

    #pragma unroll
    for (int c = 0; c < 4; c++) acc[c] = {0.f, 0.f, 0.f, 0.f};
    #pragma unroll
    for (int s = 0; s < 2; s++) {
        short8 af = *(const short8*)&Tl[(mrow + m) * 72 + s * 32 + q * 8];
        #pragma unroll
        for (int c = 0; c < 4; c++) {
            short8 bfr = *(const short8*)&W2t[(c * 16 + m) * 72 + s * 32 + q * 8];
            acc[c] = __builtin_amdgcn_mfma_f32_16x16x32_bf16(af, bfr, acc[c], 0, 0, 0);
        }
    }
    #pragma unroll
    for (int c = 0; c < 4; c++) {
        float sv = 0.f, sq = 0.f;
        #pragma unroll
        for (int r = 0; r < 4; r++) {
            float o = acc[c][r] + bias2[c];
            if (MODE == 0) o = fmaxf(o, 0.f);
            Zg[(size_t)(r0 + mrow + q * 4 + r) * HID + c * 16 + m] = f2b(o);
            if (MODE == 1) { sv += o; sq += o * o; }
        }
        if (MODE == 1) {
            sv += __shfl_xor(sv, 16); sv += __shfl_xor(sv, 32);
            sq += __shfl_xor(sq, 16); sq += __shfl_xor(sq, 32);
            if (q == 0) {
                unsafeAtomicAdd(&stats[c * 16 + m], sv);
                unsafeAtomicAdd(&stats[64 + c * 16 + m], sq);
            }
        }
    }
}

// ---------------------------------------------------------------------------
// Head: pooled = segsum over 116 rows; relu; @Wl1+bl1; @Wl2+bl2
// ---------------------------------------------------------------------------
__global__ __launch_bounds__(128) void head_kernel(
    const bf16* __restrict__ hb, const float* __restrict__ Wl1,
    const float* __restrict__ bl1, const float* __restrict__ Wl2,
    const float* __restrict__ bl2, float* __restrict__ out)
{
    __shared__ float part[2 * HID];
    __shared__ float ps[HID];
    __shared__ float r0[128], r1[128];

    const int g = blockIdx.x;
    const int tid = threadIdx.x;
    const int lane = tid & 63;
    const int wv = tid >> 6;
    const bf16* hbg = hb + (size_t)g * ROIS * HID;

    float acc = 0.f;
    for (int r = wv; r < ROIS; r += 2)
        acc += b2f(hbg[r * HID + lane]);
    part[wv * HID + lane] = acc;
    __syncthreads();
    if (tid < HID) ps[tid] = fmaxf(part[tid] + part[HID + tid], 0.f);
    __syncthreads();

    float e0 = 0.f, e1 = 0.f;
    if (tid < ROIS) {
        float a = bl1[tid];
        #pragma unroll 8
        for (int c = 0; c < HID; c++)
            a += ps[c] * Wl1[c * ROIS + tid];
        e0 = a * Wl2[tid * 2 + 0];
        e1 = a * Wl2[tid * 2 + 1];
    }
    r0[tid] = e0;
    r1[tid] = e1;
    __syncthreads();
    for (int s = 64; s > 0; s >>= 1) {
        if (tid < s) { r0[tid] += r0[tid + s]; r1[tid] += r1[tid + s]; }
        __syncthreads();
    }
    if (tid == 0) {
        out[g * 2 + 0] = r0[0] + bl2[0];
        out[g * 2 + 1] = r1[0] + bl2[1];
    }
}

// ---------------------------------------------------------------------------
extern "C" void kernel_launch(void* const* d_in, const int* in_sizes, int n_in,
                              void* d_out, int out_size, void* d_ws, size_t ws_size,
                              hipStream_t stream)
{
    const float* x       = (const float*)d_in[0];
    const float* ea      = (const float*)d_in[1];
    const int*   eidx    = (const int*)  d_in[2];
    const int*   gid     = (const int*)  d_in[4];
    const float* emb     = (const float*)d_in[5];
    const float* Wenc    = (const float*)d_in[6];
    const float* benc    = (const float*)d_in[7];
    const float* gamma_e = (const float*)d_in[8];
    const float* beta_e  = (const float*)d_in[9];
    const float* We0     = (const float*)d_in[10];
    const float* be0     = (const float*)d_in[11];
    const float* W10     = (const float*)d_in[12];
    const float* b10     = (const float*)d_in[13];
    const float* W20     = (const float*)d_in[14];
    const float* b20     = (const float*)d_in[15];
    const float* We      = (const float*)d_in[16];
    const float* be      = (const float*)d_in[17];
    const float* W1      = (const float*)d_in[18];
    const float* b1      = (const float*)d_in[19];
    const float* W2      = (const float*)d_in[20];
    const float* b2      = (const float*)d_in[21];
    const float* gamma   = (const float*)d_in[22];
    const float* beta    = (const float*)d_in[23];
    const float* Wl1     = (const float*)d_in[24];
    const float* bl1     = (const float*)d_in[25];
    const float* Wl2     = (const float*)d_in[26];
    const float* bl2     = (const float*)d_in[27];

    const int* srcp = eidx;
    const int* dstp = eidx + NEDGES;

    // workspace (~55.9 MB):
    // A (bf16 NH) | Z (bf16 NH) | perm | ssrc | cnt | off | cur | stats
    const size_t NH = (size_t)NNODES * HID;
    char* p = (char*)d_ws;
    bf16* Abuf = (bf16*)p;  p += NH * 2;
    bf16* Zbuf = (bf16*)p;  p += NH * 2;
    int* perm  = (int*)p;   p += (size_t)NEDGES * 4;
    int* ssrc  = (int*)p;   p += (size_t)NEDGES * 4;
    int* cnt   = (int*)p;   p += (size_t)NNODES * 4;
    int* off   = (int*)p;   p += (size_t)(NNODES + 16) * 4;
    int* cur   = (int*)p;   p += (size_t)NNODES * 4;
    float* stats = (float*)p;   // 512 floats

    hipMemsetAsync(cnt, 0, (size_t)NNODES * 4, stream);
    hipMemsetAsync(stats, 0, 512 * 4, stream);

    const int eb = (NEDGES + 255) / 256;            // 11719
    const int nb = (NNODES * HID + 255) / 256;      // 29696 (exact)

    // sort edges by dst (once per launch; reused by all 4 layers)
    hist_kernel<<<eb, 256, 0, stream>>>(dstp, cnt);
    scan_kernel<<<1, 1024, 0, stream>>>(cnt, off, cur);
    scatter_kernel<<<eb, 256, 0, stream>>>(srcp, dstp, cur, ssrc, perm);

    // encoder + BN
    enc_kernel<<<2048, 256, 0, stream>>>(x, gid, emb, Wenc, benc, Abuf, stats);
    bn_kernel<<<nb, 256, 0, stream>>>(Abuf, stats, gamma_e, beta_e, 0);

    // GINE layer 0: A -> Z, relu epilogue
    agg_kernel<<<nb, 256, 0, stream>>>(Abuf, Zbuf, ea, perm, ssrc, off, We0, be0);
    mlp_kernel<0><<<NNODES / 64, 256, 0, stream>>>(Zbuf, W10, b10, W20, b20, nullptr);

    // GINE layer 1: Z -> A, BN + relu
    agg_kernel<<<nb, 256, 0, stream>>>(Zbuf, Abuf, ea, perm, ssrc, off, We, be);
    mlp_kernel<1><<<NNODES / 64, 256, 0, stream>>>(Abuf, W1, b1, W2, b2, stats + 128);
    bn_kernel<<<nb, 256, 0, stream>>>(Abuf, stats + 128, gamma, beta, 1);

    // GINE layer 2: A -> Z
    agg_kernel<<<nb, 256, 0, stream>>>(Abuf, Zbuf, ea, perm, ssrc, off,
                                       We + 320, be + 64);
    mlp_kernel<1><<<NNODES / 64, 256, 0, stream>>>(Zbuf, W1 + 4096, b1 + 64,
                                                   W2 + 4096, b2 + 64, stats + 256);
    bn_kernel<<<nb, 256, 0, stream>>>(Zbuf, stats + 256, gamma, beta, 1);

    // GINE layer 3: Z -> A
    agg_kernel<<<nb, 256, 0, stream>>>(Zbuf, Abuf, ea, perm, ssrc, off,
                                       We + 640, be + 128);
    mlp_kernel<1><<<NNODES / 64, 256, 0, stream>>>(Abuf, W1 + 8192, b1 + 128,
                                                   W2 + 8192, b2 + 128, stats + 384);
    bn_kernel<<<nb, 256, 0, stream>>>(Abuf, stats + 384, gamma, beta, 1);

    // pooling + head
    head_kernel<<<NGRAPH, 128, 0, stream>>>(Abuf, Wl1, bl1, Wl2, bl2, (float*)d_out);
}

// Round 5
// 2114.257 us; speedup vs baseline: 1.8463x; 1.1334x over previous
//
#include <hip/hip_runtime.h>
#include <hip/hip_bf16.h>

typedef __hip_bfloat16 bf16;
typedef __attribute__((ext_vector_type(8))) short short8;
typedef __attribute__((ext_vector_type(4))) float floatx4;

#define NNODES 118784
#define NEDGES 3000000
#define INDIM 116
#define EMBD 16
#define HID 64
#define NGRAPH 1024
#define ROIS 116
#define KPAD 160          // 132 rounded up to 5*32 for K-steps

__device__ __forceinline__ float b2f(bf16 v) { return __bfloat162float(v); }
__device__ __forceinline__ bf16 f2b(float v) { return __float2bfloat16(v); }
__device__ __forceinline__ unsigned short f2u(float v) {
    bf16 b = __float2bfloat16(v);
    return *reinterpret_cast<unsigned short*>(&b);
}

// ---------------------------------------------------------------------------
// Sort phase 1: histogram of dst
// ---------------------------------------------------------------------------
__global__ __launch_bounds__(256) void hist_kernel(
    const int* __restrict__ dst, int* __restrict__ cnt)
{
    int i = blockIdx.x * 256 + threadIdx.x;
    if (i < NEDGES) atomicAdd(&cnt[dst[i]], 1);
}

// ---------------------------------------------------------------------------
// Sort phase 2a/2b/2c: parallel exclusive scan of 118784 counts.
// 232 blocks x 512 elements.
// ---------------------------------------------------------------------------
__global__ __launch_bounds__(256) void scan1_kernel(
    const int* __restrict__ cnt, int* __restrict__ bsum)
{
    __shared__ int sd[256];
    const int b = blockIdx.x, t = threadIdx.x;
    sd[t] = cnt[b * 512 + t] + cnt[b * 512 + t + 256];
    __syncthreads();
    for (int s = 128; s > 0; s >>= 1) {
        if (t < s) sd[t] += sd[t + s];
        __syncthreads();
    }
    if (t == 0) bsum[b] = sd[0];
}

__global__ __launch_bounds__(256) void scan2_kernel(
    const int* __restrict__ bsum, int* __restrict__ boff, int* __restrict__ offN)
{
    __shared__ int sd[256];
    const int t = threadIdx.x;
    sd[t] = (t < 232) ? bsum[t] : 0;
    __syncthreads();
    for (int d = 1; d < 256; d <<= 1) {
        int v = (t >= d) ? sd[t - d] : 0;
        __syncthreads();
        sd[t] += v;
        __syncthreads();
    }
    if (t < 232) boff[t] = (t == 0) ? 0 : sd[t - 1];
    if (t == 0) offN[0] = NEDGES;     // off[NNODES]
}

__global__ __launch_bounds__(256) void scan3_kernel(
    const int* __restrict__ cnt, const int* __restrict__ boff,
    int* __restrict__ off, int* __restrict__ cur)
{
    __shared__ int sd[256];
    const int b = blockIdx.x, t = threadIdx.x;
    const int base = b * 512;
    const int c0 = cnt[base + 2 * t], c1 = cnt[base + 2 * t + 1];
    sd[t] = c0 + c1;
    __syncthreads();
    for (int d = 1; d < 256; d <<= 1) {
        int v = (t >= d) ? sd[t - d] : 0;
        __syncthreads();
        sd[t] += v;
        __syncthreads();
    }
    const int ex = ((t == 0) ? 0 : sd[t - 1]) + boff[b];
    off[base + 2 * t] = ex;       cur[base + 2 * t] = ex;
    off[base + 2 * t + 1] = ex + c0; cur[base + 2 * t + 1] = ex + c0;
}

// ---------------------------------------------------------------------------
// Sort phase 3: scatter edges into dst-sorted order
// ---------------------------------------------------------------------------
__global__ __launch_bounds__(256) void scatter_kernel(
    const int* __restrict__ src, const int* __restrict__ dst,
    int* __restrict__ cur, int* __restrict__ ssrc, int* __restrict__ perm)
{
    int i = blockIdx.x * 256 + threadIdx.x;
    if (i >= NEDGES) return;
    int d = dst[i];
    int p = atomicAdd(&cur[d], 1);
    ssrc[p] = src[i];
    perm[p] = i;
}

// ---------------------------------------------------------------------------
// Optional phase 4: permute edge attrs into sorted order (coalesced writes)
// ---------------------------------------------------------------------------
__global__ __launch_bounds__(256) void permute_ea_kernel(
    const float* __restrict__ ea, const int* __restrict__ perm,
    float* __restrict__ sea)
{
    int p = blockIdx.x * 256 + threadIdx.x;
    if (p >= NEDGES) return;
    const float* a = ea + (size_t)perm[p] * 5;
    float* o = sea + (size_t)p * 5;
    o[0] = a[0]; o[1] = a[1]; o[2] = a[2]; o[3] = a[3]; o[4] = a[4];
}

// ---------------------------------------------------------------------------
// Encoder as MFMA GEMM: h = relu([x | emb[gid]] @ W_enc + b_enc), pre-BN,
// + per-channel sum/sumsq stats. 64 nodes/block, K padded 132->160.
// LDS layout is fragment-linear: frag (g,s) for lane l at [((g*5+s)*64+l)*8].
// ---------------------------------------------------------------------------
__global__ __launch_bounds__(256) void enc_kernel(
    const float* __restrict__ x, const int* __restrict__ gid,
    const float* __restrict__ emb, const float* __restrict__ Wenc,
    const float* __restrict__ benc,
    bf16* __restrict__ hb, float* __restrict__ stats)
{
    __shared__ unsigned short Ap[4 * 5 * 64 * 8];   // 20 KB
    __shared__ unsigned short Bp[4 * 5 * 64 * 8];   // 20 KB

    const int tid = threadIdx.x;
    const int r0 = blockIdx.x * 64;

    // A: x part (k < 116), coalesced fp32 reads
    for (int i = tid; i < 64 * INDIM; i += 256) {
        const int r = i / INDIM, k = i - r * INDIM;
        const float v = x[(size_t)(r0 + r) * INDIM + k];
        const int g = r >> 4, m = r & 15, s = k >> 5, q = (k >> 3) & 3, j = k & 7;
        Ap[(((g * 5 + s) * 64) + q * 16 + m) * 8 + j] = f2u(v);
    }
    // A: emb part (k = 116..131)
    for (int i = tid; i < 64 * EMBD; i += 256) {
        const int r = i >> 4, kk = i & 15, k = INDIM + kk;
        const float v = emb[gid[r0 + r] * EMBD + kk];
        const int g = r >> 4, m = r & 15, s = k >> 5, q = (k >> 3) & 3, j = k & 7;
        Ap[(((g * 5 + s) * 64) + q * 16 + m) * 8 + j] = f2u(v);
    }
    // A: zero pad (k = 132..159)
    for (int i = tid; i < 64 * 28; i += 256) {
        const int r = i / 28, k = 132 + (i - r * 28);
        const int g = r >> 4, m = r & 15, s = k >> 5, q = (k >> 3) & 3, j = k & 7;
        Ap[(((g * 5 + s) * 64) + q * 16 + m) * 8 + j] = 0;
    }
    // B: W part (k < 132), Wenc row-major [132][64]
    for (int i = tid; i < 132 * 64; i += 256) {
        const int k = i >> 6, n = i & 63;
        const float v = Wenc[i];
        const int c = n >> 4, m = n & 15, s = k >> 5, q = (k >> 3) & 3, j = k & 7;
        Bp[(((c * 5 + s) * 64) + q * 16 + m) * 8 + j] = f2u(v);
    }
    // B: zero pad
    for (int i = tid; i < 28 * 64; i += 256) {
        const int k = 132 + (i >> 6), n = i & 63;
        const int c = n >> 4, m = n & 15, s = k >> 5, q = (k >> 3) & 3, j = k & 7;
        Bp[(((c * 5 + s) * 64) + q * 16 + m) * 8 + j] = 0;
    }
    __syncthreads();

    const int lane = tid & 63;
    const int wv   = tid >> 6;
    const int m    = lane & 15;
    const int q    = lane >> 4;

    floatx4 acc[4];
    #pragma unroll
    for (int c = 0; c < 4; c++) acc[c] = {0.f, 0.f, 0.f, 0.f};

    #pragma unroll
    for (int s = 0; s < 5; s++) {
        short8 af = *(const short8*)&Ap[((wv * 5 + s) * 64 + lane) * 8];
        #pragma unroll
        for (int c = 0; c < 4; c++) {
            short8 bfr = *(const short8*)&Bp[((c * 5 + s) * 64 + lane) * 8];
            acc[c] = __builtin_amdgcn_mfma_f32_16x16x32_bf16(af, bfr, acc[c], 0, 0, 0);
        }
    }

    #pragma unroll
    for (int c = 0; c < 4; c++) {
        const int ch = c * 16 + m;
        const float bb = benc[ch];
        float sv = 0.f, sq = 0.f;
        #pragma unroll
        for (int r = 0; r < 4; r++) {
            const int row = r0 + wv * 16 + q * 4 + r;
            float a = fmaxf(acc[c][r] + bb, 0.f);
            hb[(size_t)row * HID + ch] = f2b(a);
            sv += a; sq += a * a;
        }
        sv += __shfl_xor(sv, 16); sv += __shfl_xor(sv, 32);
        sq += __shfl_xor(sq, 16); sq += __shfl_xor(sq, 32);
        if (q == 0) {
            unsafeAtomicAdd(&stats[ch], sv);
            unsafeAtomicAdd(&stats[64 + ch], sq);
        }
    }
}

// ---------------------------------------------------------------------------
// BN finalize in place, optional relu
// ---------------------------------------------------------------------------
__global__ __launch_bounds__(256) void bn_kernel(
    bf16* __restrict__ hb, const float* __restrict__ stats,
    const float* __restrict__ gamma, const float* __restrict__ beta, int relu)
{
    const int idx = blockIdx.x * 256 + threadIdx.x;
    if (idx >= NNODES * HID) return;
    const int c = idx & 63;
    const float m   = stats[c] * (1.f / NNODES);
    const float var = stats[64 + c] * (1.f / NNODES) - m * m;
    const float inv = rsqrtf(var + 1e-5f);
    const float gg = gamma[c] * inv;
    const float bb = beta[c] - gg * m;
    float v = b2f(hb[idx]) * gg + bb;
    if (relu) v = fmaxf(v, 0.f);
    hb[idx] = f2b(v);
}

// ---------------------------------------------------------------------------
// Gather-aggregate: wave per node, lane = channel, 4-deep gather pipeline.
// SORTED_EA=1: edge attrs pre-permuted (sea, sequential). 0: via perm.
// ---------------------------------------------------------------------------
template <int SORTED_EA>
__global__ __launch_bounds__(256) void agg_kernel(
    const bf16* __restrict__ hin, bf16* __restrict__ zout,
    const float* __restrict__ eat, const int* __restrict__ perm,
    const int* __restrict__ ssrc, const int* __restrict__ off,
    const float* __restrict__ We, const float* __restrict__ be)
{
    const int lane = threadIdx.x & 63;
    const int node = (blockIdx.x * 256 + threadIdx.x) >> 6;
    if (node >= NNODES) return;

    const float w0 = We[0 * 64 + lane];
    const float w1 = We[1 * 64 + lane];
    const float w2 = We[2 * 64 + lane];
    const float w3 = We[3 * 64 + lane];
    const float w4 = We[4 * 64 + lane];
    const float bb = be[lane];

    const int s0 = off[node];
    const int s1 = off[node + 1];
    const float self = b2f(hin[(size_t)node * HID + lane]);

    float acc = 0.f;
    int i = s0;
    for (; i + 4 <= s1; i += 4) {
        const int sA = ssrc[i], sB = ssrc[i + 1], sC = ssrc[i + 2], sD = ssrc[i + 3];
        const float hA = b2f(hin[(size_t)sA * HID + lane]);
        const float hB = b2f(hin[(size_t)sB * HID + lane]);
        const float hC = b2f(hin[(size_t)sC * HID + lane]);
        const float hD = b2f(hin[(size_t)sD * HID + lane]);
        const float* aA = SORTED_EA ? (eat + (size_t)i * 5)
                                    : (eat + (size_t)perm[i] * 5);
        const float* aB = SORTED_EA ? (aA + 5) : (eat + (size_t)perm[i + 1] * 5);
        const float* aC = SORTED_EA ? (aA + 10) : (eat + (size_t)perm[i + 2] * 5);
        const float* aD = SORTED_EA ? (aA + 15) : (eat + (size_t)perm[i + 3] * 5);
        float vA = bb + aA[0]*w0 + aA[1]*w1 + aA[2]*w2 + aA[3]*w3 + aA[4]*w4 + hA;
        float vB = bb + aB[0]*w0 + aB[1]*w1 + aB[2]*w2 + aB[3]*w3 + aB[4]*w4 + hB;
        float vC = bb + aC[0]*w0 + aC[1]*w1 + aC[2]*w2 + aC[3]*w3 + aC[4]*w4 + hC;
        float vD = bb + aD[0]*w0 + aD[1]*w1 + aD[2]*w2 + aD[3]*w3 + aD[4]*w4 + hD;
        acc += fmaxf(vA, 0.f) + fmaxf(vB, 0.f) + fmaxf(vC, 0.f) + fmaxf(vD, 0.f);
    }
    for (; i < s1; i++) {
        const int s = ssrc[i];
        const float h = b2f(hin[(size_t)s * HID + lane]);
        const float* a = SORTED_EA ? (eat + (size_t)i * 5)
                                   : (eat + (size_t)perm[i] * 5);
        float v = bb + a[0]*w0 + a[1]*w1 + a[2]*w2 + a[3]*w3 + a[4]*w4 + h;
        acc += fmaxf(v, 0.f);
    }
    zout[(size_t)node * HID + lane] = f2b(self + acc);
}

// ---------------------------------------------------------------------------
// Node MLP via MFMA, in place on Z: o = relu(z@W1+b1)@W2+b2
// MODE 0: z <- relu(o).  MODE 1: z <- o (pre-BN) + stats.
// ---------------------------------------------------------------------------
template <int MODE>
__global__ __launch_bounds__(256) void mlp_kernel(
    bf16* __restrict__ Zg,
    const float* __restrict__ W1, const float* __restrict__ b1,
    const float* __restrict__ W2, const float* __restrict__ b2,
    float* __restrict__ stats)
{
    __shared__ unsigned short Zl[64 * 72];
    __shared__ unsigned short W1t[64 * 72];
    __shared__ unsigned short W2t[64 * 72];
    __shared__ unsigned short Tl[64 * 72];

    const int tid = threadIdx.x;
    const int r0 = blockIdx.x * 64;

    for (int i = tid; i < 4096; i += 256) {
        int k = i >> 6, n = i & 63;
        W1t[n * 72 + k] = f2u(W1[i]);
        W2t[n * 72 + k] = f2u(W2[i]);
    }
    {
        const uint4* zg = (const uint4*)(Zg + (size_t)r0 * HID);
        for (int i = tid; i < 512; i += 256) {
            int row = i >> 3, ch = i & 7;
            uint4 v = zg[row * 8 + ch];
            *(uint4*)&Zl[row * 72 + ch * 8] = v;
        }
    }
    __syncthreads();

    const int lane = tid & 63;
    const int wv   = tid >> 6;
    const int m    = lane & 15;
    const int q    = lane >> 4;
    const int mrow = wv * 16;

    float bias1[4], bias2[4];
    #pragma unroll
    for (int c = 0; c < 4; c++) {
        bias1[c] = b1[c * 16 + m];
        bias2[c] = b2[c * 16 + m];
    }

    floatx4 acc[4];
    #pragma unroll
    for (int c = 0; c < 4; c++) acc[c] = {0.f, 0.f, 0.f, 0.f};
    #pragma unroll
    for (int s = 0; s < 2; s++) {
        short8 af = *(const short8*)&Zl[(mrow + m) * 72 + s * 32 + q * 8];
        #pragma unroll
        for (int c = 0; c < 4; c++) {
            short8 bfr = *(const short8*)&W1t[(c * 16 + m) * 72 + s * 32 + q * 8];
            acc[c] = __builtin_amdgcn_mfma_f32_16x16x32_bf16(af, bfr, acc[c], 0, 0, 0);
        }
    }
    #pragma unroll
    for (int c = 0; c < 4; c++)
        #pragma unroll
        for (int r = 0; r < 4; r++)
            Tl[(mrow + q * 4 + r) * 72 + c * 16 + m] =
                f2u(fmaxf(acc[c][r] + bias1[c], 0.f));
    __syncthreads();

    #pragma unroll
    for (int c = 0; c < 4; c++) acc[c] = {0.f, 0.f, 0.f, 0.f};
    #pragma unroll
    for (int s = 0; s < 2; s++) {
        short8 af = *(const short8*)&Tl[(mrow + m) * 72 + s * 32 + q * 8];
        #pragma unroll
        for (int c = 0; c < 4; c++) {
            short8 bfr = *(const short8*)&W2t[(c * 16 + m) * 72 + s * 32 + q * 8];
            acc[c] = __builtin_amdgcn_mfma_f32_16x16x32_bf16(af, bfr, acc[c], 0, 0, 0);
        }
    }
    #pragma unroll
    for (int c = 0; c < 4; c++) {
        float sv = 0.f, sq = 0.f;
        #pragma unroll
        for (int r = 0; r < 4; r++) {
            float o = acc[c][r] + bias2[c];
            if (MODE == 0) o = fmaxf(o, 0.f);
            Zg[(size_t)(r0 + mrow + q * 4 + r) * HID + c * 16 + m] = f2b(o);
            if (MODE == 1) { sv += o; sq += o * o; }
        }
        if (MODE == 1) {
            sv += __shfl_xor(sv, 16); sv += __shfl_xor(sv, 32);
            sq += __shfl_xor(sq, 16); sq += __shfl_xor(sq, 32);
            if (q == 0) {
                unsafeAtomicAdd(&stats[c * 16 + m], sv);
                unsafeAtomicAdd(&stats[64 + c * 16 + m], sq);
            }
        }
    }
}

// ---------------------------------------------------------------------------
// Head
// ---------------------------------------------------------------------------
__global__ __launch_bounds__(128) void head_kernel(
    const bf16* __restrict__ hb, const float* __restrict__ Wl1,
    const float* __restrict__ bl1, const float* __restrict__ Wl2,
    const float* __restrict__ bl2, float* __restrict__ out)
{
    __shared__ float part[2 * HID];
    __shared__ float ps[HID];
    __shared__ float r0[128], r1[128];

    const int g = blockIdx.x;
    const int tid = threadIdx.x;
    const int lane = tid & 63;
    const int wv = tid >> 6;
    const bf16* hbg = hb + (size_t)g * ROIS * HID;

    float acc = 0.f;
    for (int r = wv; r < ROIS; r += 2)
        acc += b2f(hbg[r * HID + lane]);
    part[wv * HID + lane] = acc;
    __syncthreads();
    if (tid < HID) ps[tid] = fmaxf(part[tid] + part[HID + tid], 0.f);
    __syncthreads();

    float e0 = 0.f, e1 = 0.f;
    if (tid < ROIS) {
        float a = bl1[tid];
        #pragma unroll 8
        for (int c = 0; c < HID; c++)
            a += ps[c] * Wl1[c * ROIS + tid];
        e0 = a * Wl2[tid * 2 + 0];
        e1 = a * Wl2[tid * 2 + 1];
    }
    r0[tid] = e0;
    r1[tid] = e1;
    __syncthreads();
    for (int s = 64; s > 0; s >>= 1) {
        if (tid < s) { r0[tid] += r0[tid + s]; r1[tid] += r1[tid + s]; }
        __syncthreads();
    }
    if (tid == 0) {
        out[g * 2 + 0] = r0[0] + bl2[0];
        out[g * 2 + 1] = r1[0] + bl2[1];
    }
}

// ---------------------------------------------------------------------------
extern "C" void kernel_launch(void* const* d_in, const int* in_sizes, int n_in,
                              void* d_out, int out_size, void* d_ws, size_t ws_size,
                              hipStream_t stream)
{
    const float* x       = (const float*)d_in[0];
    const float* ea      = (const float*)d_in[1];
    const int*   eidx    = (const int*)  d_in[2];
    const int*   gid     = (const int*)  d_in[4];
    const float* emb     = (const float*)d_in[5];
    const float* Wenc    = (const float*)d_in[6];
    const float* benc    = (const float*)d_in[7];
    const float* gamma_e = (const float*)d_in[8];
    const float* beta_e  = (const float*)d_in[9];
    const float* We0     = (const float*)d_in[10];
    const float* be0     = (const float*)d_in[11];
    const float* W10     = (const float*)d_in[12];
    const float* b10     = (const float*)d_in[13];
    const float* W20     = (const float*)d_in[14];
    const float* b20     = (const float*)d_in[15];
    const float* We      = (const float*)d_in[16];
    const float* be      = (const float*)d_in[17];
    const float* W1      = (const float*)d_in[18];
    const float* b1      = (const float*)d_in[19];
    const float* W2      = (const float*)d_in[20];
    const float* b2      = (const float*)d_in[21];
    const float* gamma   = (const float*)d_in[22];
    const float* beta    = (const float*)d_in[23];
    const float* Wl1     = (const float*)d_in[24];
    const float* bl1     = (const float*)d_in[25];
    const float* Wl2     = (const float*)d_in[26];
    const float* bl2     = (const float*)d_in[27];

    const int* srcp = eidx;
    const int* dstp = eidx + NEDGES;

    const size_t NH = (size_t)NNODES * HID;
    char* p = (char*)d_ws;
    bf16* Abuf = (bf16*)p;  p += NH * 2;
    bf16* Zbuf = (bf16*)p;  p += NH * 2;
    int* perm  = (int*)p;   p += (size_t)NEDGES * 4;
    int* ssrc  = (int*)p;   p += (size_t)NEDGES * 4;
    int* cnt   = (int*)p;   p += (size_t)NNODES * 4;
    int* off   = (int*)p;   p += (size_t)(NNODES + 16) * 4;
    int* cur   = (int*)p;   p += (size_t)NNODES * 4;
    int* bsum  = (int*)p;   p += 256 * 4;
    int* boff  = (int*)p;   p += 256 * 4;
    float* stats = (float*)p; p += 512 * 4;
    float* sea = (float*)p;   // optional: NEDGES*5 fp32 = 60 MB
    const size_t need_sea = (size_t)(p - (char*)d_ws) + (size_t)NEDGES * 5 * 4;
    const int use_sea = (ws_size >= need_sea) ? 1 : 0;   // constant across calls

    hipMemsetAsync(cnt, 0, (size_t)NNODES * 4, stream);
    hipMemsetAsync(stats, 0, 512 * 4, stream);

    const int eb = (NEDGES + 255) / 256;
    const int nb = (NNODES * HID + 255) / 256;    // elementwise grids
    const int tb = NNODES / 64;                   // 1856 tile blocks

    // ---- sort edges by dst ----
    hist_kernel<<<eb, 256, 0, stream>>>(dstp, cnt);
    scan1_kernel<<<232, 256, 0, stream>>>(cnt, bsum);
    scan2_kernel<<<1, 256, 0, stream>>>(bsum, boff, off + NNODES);
    scan3_kernel<<<232, 256, 0, stream>>>(cnt, boff, off, cur);
    scatter_kernel<<<eb, 256, 0, stream>>>(srcp, dstp, cur, ssrc, perm);
    if (use_sea)
        permute_ea_kernel<<<eb, 256, 0, stream>>>(ea, perm, sea);

    // ---- encoder + BN ----
    enc_kernel<<<tb, 256, 0, stream>>>(x, gid, emb, Wenc, benc, Abuf, stats);
    bn_kernel<<<nb, 256, 0, stream>>>(Abuf, stats, gamma_e, beta_e, 0);

    const float* eat = use_sea ? sea : ea;

    // ---- GINE layer 0: A -> Z, relu ----
    if (use_sea)
        agg_kernel<1><<<nb, 256, 0, stream>>>(Abuf, Zbuf, eat, perm, ssrc, off, We0, be0);
    else
        agg_kernel<0><<<nb, 256, 0, stream>>>(Abuf, Zbuf, eat, perm, ssrc, off, We0, be0);
    mlp_kernel<0><<<tb, 256, 0, stream>>>(Zbuf, W10, b10, W20, b20, nullptr);

    // ---- GINE layers 1..3: BN + relu ----
    bf16* bufs[2] = {Zbuf, Abuf};
    for (int l = 0; l < 3; l++) {
        bf16* src_ = bufs[l & 1];
        bf16* dst_ = bufs[(l & 1) ^ 1];
        if (use_sea)
            agg_kernel<1><<<nb, 256, 0, stream>>>(src_, dst_, eat, perm, ssrc, off,
                                                  We + l * 320, be + l * 64);
        else
            agg_kernel<0><<<nb, 256, 0, stream>>>(src_, dst_, eat, perm, ssrc, off,
                                                  We + l * 320, be + l * 64);
        mlp_kernel<1><<<tb, 256, 0, stream>>>(dst_, W1 + l * 4096, b1 + l * 64,
                                              W2 + l * 4096, b2 + l * 64,
                                              stats + 128 * (l + 1));
        bn_kernel<<<nb, 256, 0, stream>>>(dst_, stats + 128 * (l + 1), gamma, beta, 1);
    }

    // final buffer after 3 layers: bufs[1^1]... layer2 wrote bufs[1], i.e. Abuf
    head_kernel<<<NGRAPH, 128, 0, stream>>>(Abuf, Wl1, bl1, Wl2, bl2, (float*)d_out);
}